// Round 12
// baseline (250.324 us; speedup 1.0000x reference)
//
#include <hip/hip_runtime.h>

// SigLIP contrastive loss:
//   logits = emb1 @ emb2^T / 0.07           [B,B], B=8192, D=1024
//   loss = ( sum_i softplus(-l_ii) + sum_{i!=j} softplus(l_ij) ) / B
// R12: arithmetic intensity vs L2. R8-R11 plateau was L2 staging BW: 128-col
// tiles pull 128 KB/CU/K-tile (~2340 cyc @56 B/cyc) vs 1104 cyc MFMA.
// 256x256 tile, 16 waves (1024 thr), same per-wave shape as R11 (64x64 acc,
// 88 VGPR proven): staging halves to 64 KB/K-tile (~1170 cyc) < MFMA 2208
// cyc/SIMD -> MFMA-bound. Data plane unchanged: fp8 bricks, conflict-free
// lane*16 frag reads, stage-early + vmcnt(0)-late, 1 barrier/K-tile.

#define B_DIM 8192
#define K_DIM 1024
#define BT 256                 // tile rows == cols
#define BKB 128                // K bytes per K-tile
#define NT (K_DIM / BKB)       // 8 K-tiles
#define BRICK 16384            // one (128-row panel, K-tile) brick
#define PANEL_BYTES (NT * BRICK)
#define BUFSZ 65536            // LDS buffer: A0 16K | A1 16K | B0 16K | B1 16K

typedef int i32x4 __attribute__((ext_vector_type(4)));
typedef int i32x8 __attribute__((ext_vector_type(8)));
typedef float f32x4 __attribute__((ext_vector_type(4)));

// f32 -> fp8 e4m3 brick permutation (PANEL=128). One thread = 16 out bytes.
// Brick offset = fb*2048 + h*1024 + kch*256 + lr*16.
// Source: row = p*128 + fb*16 + lr, k byte = t*128 + kch*32 + h*16.
__device__ __forceinline__ void brick_store(const float* __restrict__ in,
                                            unsigned char* __restrict__ out,
                                            float scale, int i) {
  const int o = i * 16;
  const int b = o >> 14;                  // brick index
  const int p = b >> 3, t = b & 7;        // panel, K-tile
  const int w = o & (BRICK - 1);
  const int fb = w >> 11;
  const int h = (w >> 10) & 1;
  const int kch = (w >> 8) & 3;
  const int lr = (w >> 4) & 15;
  const int row = p * 128 + fb * 16 + lr;
  const int kb = t * 128 + kch * 32 + h * 16;
  const float4* src = (const float4*)(in + (size_t)row * K_DIM + kb);
  float4 v0 = src[0], v1 = src[1], v2 = src[2], v3 = src[3];
  unsigned w0 = 0, w1 = 0, w2 = 0, w3 = 0;
  w0 = __builtin_amdgcn_cvt_pk_fp8_f32(v0.x * scale, v0.y * scale, w0, 0);
  w0 = __builtin_amdgcn_cvt_pk_fp8_f32(v0.z * scale, v0.w * scale, w0, 1);
  w1 = __builtin_amdgcn_cvt_pk_fp8_f32(v1.x * scale, v1.y * scale, w1, 0);
  w1 = __builtin_amdgcn_cvt_pk_fp8_f32(v1.z * scale, v1.w * scale, w1, 1);
  w2 = __builtin_amdgcn_cvt_pk_fp8_f32(v2.x * scale, v2.y * scale, w2, 0);
  w2 = __builtin_amdgcn_cvt_pk_fp8_f32(v2.z * scale, v2.w * scale, w2, 1);
  w3 = __builtin_amdgcn_cvt_pk_fp8_f32(v3.x * scale, v3.y * scale, w3, 0);
  w3 = __builtin_amdgcn_cvt_pk_fp8_f32(v3.z * scale, v3.w * scale, w3, 1);
  *(uint4*)(out + o) = make_uint4(w0, w1, w2, w3);
}

__global__ __launch_bounds__(256) void cvt_fused(
    const float* __restrict__ e1, const float* __restrict__ e2,
    unsigned char* __restrict__ A8, unsigned char* __restrict__ B8,
    int nbA, float scaleA) {
  const int blk = blockIdx.x;
  if (blk < nbA)
    brick_store(e1, A8, scaleA, blk * 256 + threadIdx.x);
  else
    brick_store(e2, B8, 1.0f, (blk - nbA) * 256 + threadIdx.x);
}

// Cheap softplus accumulate: softplus(x) = max(x,0) + log(1+exp(-|x|)).
template <bool DIAG>
__device__ __forceinline__ float softplus_sum(const f32x4 (&acc)[4][4],
                                              int rbase, int cbase) {
  float lin = 0.f, cor = 0.f;
#pragma unroll
  for (int m = 0; m < 4; ++m) {
#pragma unroll
    for (int n = 0; n < 4; ++n) {
#pragma unroll
      for (int r = 0; r < 4; ++r) {
        float x = acc[m][n][r];
        if (DIAG) {
          int row = rbase + m * 16 + r;
          int col = cbase + n * 16;
          if (row == col) x = -x;  // diagonal: softplus(-l_ii)
        }
        lin += fmaxf(x, 0.f);
        cor += __logf(1.f + __expf(-fabsf(x)));
      }
    }
  }
  return lin + cor;
}

// Staging: 64 KB/K-tile = 64 linear 1024B slices. Wave w covers region
// r = w>>2 (A-panel0, A-panel1, B-panel0, B-panel1), slices (w&3)*4 + q.
// srcP/dstoff precomputed per wave; Q and TI compile-time after unroll.
#define STAGE(SB, Q, TI)                                                      \
  __builtin_amdgcn_global_load_lds(                                           \
      (const __attribute__((address_space(1))) void*)(const void*)(           \
          srcP + (TI) * BRICK + (Q) * 1024),                                  \
      (__attribute__((address_space(3))) void*)(void*)(                       \
          lds + (SB) + dstoff + (Q) * 1024),                                  \
      16, 0, 0)

// Fragment read: two conflict-free ds_read_b128 (lane*16 stride) + combine.
#define LDA(OUT, RB, M)                                                       \
  {                                                                           \
    const unsigned char* _b = ldsL + ((RB) + aoff + ((M) << 11));             \
    i32x4 _lo = *(const i32x4*)(_b);                                          \
    i32x4 _hi = *(const i32x4*)(_b + 1024);                                   \
    OUT = __builtin_shufflevector(_lo, _hi, 0, 1, 2, 3, 4, 5, 6, 7);          \
  }
#define LDB(OUT, RB, N)                                                       \
  {                                                                           \
    const unsigned char* _b = ldsL + ((RB) + boff + ((N) << 11));             \
    i32x4 _lo = *(const i32x4*)(_b);                                          \
    i32x4 _hi = *(const i32x4*)(_b + 1024);                                   \
    OUT = __builtin_shufflevector(_lo, _hi, 0, 1, 2, 3, 4, 5, 6, 7);          \
  }

#define MFMA(AF, BF, M, N)                                                    \
  acc[M][N] = __builtin_amdgcn_mfma_scale_f32_16x16x128_f8f6f4(               \
      AF, BF, acc[M][N], 0, 0, 0, 127, 0, 127)

__global__ __launch_bounds__(1024, 1) void siglip_gemm(
    const unsigned char* __restrict__ A8,
    const unsigned char* __restrict__ B8,
    float* __restrict__ partials) {
  __shared__ unsigned char lds[2 * BUFSZ];  // 128 KB double buffer
  __shared__ float wsum[16];

  const int tid = threadIdx.x;
  const int wave = tid >> 6;
  const int lane = tid & 63;
  const int wr = wave >> 2;  // 0..3 -> 64-row strip
  const int wc = wave & 3;   // 0..3 -> 64-col strip
  const int brow = blockIdx.y;
  const int bcol = blockIdx.x;

  f32x4 acc[4][4];
#pragma unroll
  for (int m = 0; m < 4; ++m)
#pragma unroll
    for (int n = 0; n < 4; ++n) acc[m][n] = f32x4{0.f, 0.f, 0.f, 0.f};

  // Staging assignment: region r = wave>>2 maps to {A panel 2*brow,
  // A panel 2*brow+1, B panel 2*bcol, B panel 2*bcol+1}.
  const int sreg = wave >> 2;
  const int ssub = wave & 3;
  const unsigned char* srcP =
      (sreg < 2 ? A8 + (size_t)(2 * brow + sreg) * PANEL_BYTES
                : B8 + (size_t)(2 * bcol + (sreg - 2)) * PANEL_BYTES) +
      ssub * 4096 + (lane << 4);
  const int dstoff = sreg * 16384 + ssub * 4096;

  // Fragment-read bases: A region (wr>>1), sub-panel (wr&1); B likewise.
  const int aoff = (wr >> 1) * 16384 + ((wr & 1) * 4) * 2048;
  const int boff = 32768 + (wc >> 1) * 16384 + ((wc & 1) * 4) * 2048;
  const unsigned char* ldsL = lds + (lane << 4);  // per-lane read base

  // Prologue: stage tile 0 into buf 0, full drain, publish.
  STAGE(0, 0, 0); STAGE(0, 1, 0); STAGE(0, 2, 0); STAGE(0, 3, 0);
  asm volatile("s_waitcnt vmcnt(0)" ::: "memory");
  __builtin_amdgcn_s_barrier();
  __builtin_amdgcn_sched_barrier(0);

#pragma unroll
  for (int T = 0; T < NT; ++T) {
    const int rb = (T & 1) * BUFSZ;   // read buffer (tile T)
    const int sb = rb ^ BUFSZ;        // stage buffer (tile T+1; held T-1)

    // Fragment reads for tile T (16x ds_read_b128, conflict-free, imm offs).
    i32x8 b0, b1, b2, b3, a0, a1, a2, a3;
    LDB(b0, rb, 0); LDB(b1, rb, 1); LDB(b2, rb, 2); LDB(b3, rb, 3);
    LDA(a0, rb, 0); LDA(a1, rb, 1); LDA(a2, rb, 2); LDA(a3, rb, 3);

    // Stage tile T+1 early; latency hides under the MFMA cluster below.
    if (T < NT - 1) {
      STAGE(sb, 0, T + 1); STAGE(sb, 1, T + 1);
      STAGE(sb, 2, T + 1); STAGE(sb, 3, T + 1);
    }
    __builtin_amdgcn_sched_barrier(0);  // pin stage issue before MFMAs

    __builtin_amdgcn_s_setprio(1);
    MFMA(a0, b0, 0, 0); MFMA(a0, b1, 0, 1); MFMA(a0, b2, 0, 2); MFMA(a0, b3, 0, 3);
    MFMA(a1, b0, 1, 0); MFMA(a1, b1, 1, 1); MFMA(a1, b2, 1, 2); MFMA(a1, b3, 1, 3);
    MFMA(a2, b0, 2, 0); MFMA(a2, b1, 2, 1); MFMA(a2, b2, 2, 2); MFMA(a2, b3, 2, 3);
    MFMA(a3, b0, 3, 0); MFMA(a3, b1, 3, 1); MFMA(a3, b2, 3, 2); MFMA(a3, b3, 3, 3);
    __builtin_amdgcn_s_setprio(0);

    if (T < NT - 1) {
      // Own staging landed (~16 MFMAs of latency cover); barrier publishes
      // all waves' staging and certifies tile T consumed.
      asm volatile("s_waitcnt vmcnt(0)" ::: "memory");
      __builtin_amdgcn_s_barrier();
      __builtin_amdgcn_sched_barrier(0);
    }
  }

  // Epilogue. C/D 16x16 map: col = lane&15, row = (lane>>4)*4 + r.
  const int rbase = brow * BT + wr * 64 + (lane >> 4) * 4;
  const int cbase = bcol * BT + wc * 64 + (lane & 15);
  float lsum;
  if (brow == bcol)
    lsum = softplus_sum<true>(acc, rbase, cbase);
  else
    lsum = softplus_sum<false>(acc, rbase, cbase);

#pragma unroll
  for (int off = 32; off > 0; off >>= 1) lsum += __shfl_down(lsum, off);
  __syncthreads();
  if (lane == 0) wsum[wave] = lsum;
  __syncthreads();
  if (tid == 0) {
    float s = 0.f;
#pragma unroll
    for (int w = 0; w < 16; ++w) s += wsum[w];
    partials[blockIdx.y * gridDim.x + blockIdx.x] = s;
  }
}

__global__ void reduce_kernel(const float* __restrict__ partials, int n,
                              float* __restrict__ out) {
  __shared__ float s[256];
  float v = 0.f;
  for (int i = threadIdx.x; i < n; i += 256) v += partials[i];
  s[threadIdx.x] = v;
  __syncthreads();
  for (int off = 128; off > 0; off >>= 1) {
    if ((int)threadIdx.x < off) s[threadIdx.x] += s[threadIdx.x + off];
    __syncthreads();
  }
  if (threadIdx.x == 0) out[0] = s[0] / (float)B_DIM;
}

extern "C" void kernel_launch(void* const* d_in, const int* in_sizes, int n_in,
                              void* d_out, int out_size, void* d_ws, size_t ws_size,
                              hipStream_t stream) {
  const float* emb1 = (const float*)d_in[0];
  const float* emb2 = (const float*)d_in[1];

  unsigned char* A8 = (unsigned char*)d_ws;                // 8 MB (bricked)
  unsigned char* B8 = A8 + (size_t)B_DIM * K_DIM;          // 8 MB (bricked)
  float* partials = (float*)(B8 + (size_t)B_DIM * K_DIM);  // 4 KB

  const float INV_T = 1.0f / 0.07f;
  const int nbA = (B_DIM * K_DIM / 16) / 256;  // 2048 blocks per operand
  cvt_fused<<<2 * nbA, 256, 0, stream>>>(emb1, emb2, A8, B8, nbA, INV_T);

  dim3 grid(B_DIM / BT, B_DIM / BT);  // 32 x 32
  siglip_gemm<<<grid, 1024, 0, stream>>>(A8, B8, partials);

  const int nparts = (B_DIM / BT) * (B_DIM / BT);
  reduce_kernel<<<1, 256, 0, stream>>>(partials, nparts, (float*)d_out);
}

// Round 13
// 115.557 us; speedup vs baseline: 2.1662x; 2.1662x over previous
//
#include <hip/hip_runtime.h>

// SigLIP contrastive loss:
//   logits = emb1 @ emb2^T / 0.07           [B,B], B=8192, D=1024
//   loss = ( sum_i softplus(-l_ii) + sum_{i!=j} softplus(l_ij) ) / B
// R13: R11 shell (128x128, 4 waves, 64KB dbuf, 2 blocks/CU, fp8 bricks,
// conflict-free lane*16 reads) with the read->MFMA serialization removed:
// no sched_barrier between ds_reads and MFMAs (compiler interleaves with
// counted lgkmcnt), reads issued in consumption order. R8-R12 all made the
// first MFMA wait on ~13/16 reads (~1500 cyc); overlap brings the K-tile
// period toward max(LDS 1536, MFMA 1104) instead of their sum.

#define B_DIM 8192
#define K_DIM 1024
#define BT 128                 // tile rows == cols
#define BKB 128                // K bytes per K-tile
#define NT (K_DIM / BKB)       // 8 K-tiles
#define BRICK 16384            // one (128-row panel, K-tile) brick
#define PANEL_BYTES (NT * BRICK)
#define BUFSZ 32768            // LDS buffer: A 16K + B 16K

typedef int i32x4 __attribute__((ext_vector_type(4)));
typedef int i32x8 __attribute__((ext_vector_type(8)));
typedef float f32x4 __attribute__((ext_vector_type(4)));

// f32 -> fp8 e4m3 brick permutation (PANEL=128). One thread = 16 out bytes.
// Brick offset = fb*2048 + h*1024 + kch*256 + lr*16.
// Source: row = p*128 + fb*16 + lr, k byte = t*128 + kch*32 + h*16.
__device__ __forceinline__ void brick_store(const float* __restrict__ in,
                                            unsigned char* __restrict__ out,
                                            float scale, int i) {
  const int o = i * 16;
  const int b = o >> 14;                  // brick index
  const int p = b >> 3, t = b & 7;        // panel, K-tile
  const int w = o & (BRICK - 1);
  const int fb = w >> 11;
  const int h = (w >> 10) & 1;
  const int kch = (w >> 8) & 3;
  const int lr = (w >> 4) & 15;
  const int row = p * 128 + fb * 16 + lr;
  const int kb = t * 128 + kch * 32 + h * 16;
  const float4* src = (const float4*)(in + (size_t)row * K_DIM + kb);
  float4 v0 = src[0], v1 = src[1], v2 = src[2], v3 = src[3];
  unsigned w0 = 0, w1 = 0, w2 = 0, w3 = 0;
  w0 = __builtin_amdgcn_cvt_pk_fp8_f32(v0.x * scale, v0.y * scale, w0, 0);
  w0 = __builtin_amdgcn_cvt_pk_fp8_f32(v0.z * scale, v0.w * scale, w0, 1);
  w1 = __builtin_amdgcn_cvt_pk_fp8_f32(v1.x * scale, v1.y * scale, w1, 0);
  w1 = __builtin_amdgcn_cvt_pk_fp8_f32(v1.z * scale, v1.w * scale, w1, 1);
  w2 = __builtin_amdgcn_cvt_pk_fp8_f32(v2.x * scale, v2.y * scale, w2, 0);
  w2 = __builtin_amdgcn_cvt_pk_fp8_f32(v2.z * scale, v2.w * scale, w2, 1);
  w3 = __builtin_amdgcn_cvt_pk_fp8_f32(v3.x * scale, v3.y * scale, w3, 0);
  w3 = __builtin_amdgcn_cvt_pk_fp8_f32(v3.z * scale, v3.w * scale, w3, 1);
  *(uint4*)(out + o) = make_uint4(w0, w1, w2, w3);
}

__global__ __launch_bounds__(256) void cvt_fused(
    const float* __restrict__ e1, const float* __restrict__ e2,
    unsigned char* __restrict__ A8, unsigned char* __restrict__ B8,
    int nbA, float scaleA) {
  const int blk = blockIdx.x;
  if (blk < nbA)
    brick_store(e1, A8, scaleA, blk * 256 + threadIdx.x);
  else
    brick_store(e2, B8, 1.0f, (blk - nbA) * 256 + threadIdx.x);
}

// Cheap softplus accumulate: softplus(x) = max(x,0) + log(1+exp(-|x|)).
template <bool DIAG>
__device__ __forceinline__ float softplus_sum(const f32x4 (&acc)[4][4],
                                              int rbase, int cbase) {
  float lin = 0.f, cor = 0.f;
#pragma unroll
  for (int m = 0; m < 4; ++m) {
#pragma unroll
    for (int n = 0; n < 4; ++n) {
#pragma unroll
      for (int r = 0; r < 4; ++r) {
        float x = acc[m][n][r];
        if (DIAG) {
          int row = rbase + m * 16 + r;
          int col = cbase + n * 16;
          if (row == col) x = -x;  // diagonal: softplus(-l_ii)
        }
        lin += fmaxf(x, 0.f);
        cor += __logf(1.f + __expf(-fabsf(x)));
      }
    }
  }
  return lin + cor;
}

// Staging: 32 KB/K-tile as 32 linear 1024B slices (A 16, B 16); wave w takes
// slices w*4..w*4+3 of each operand. srcA/srcB include wave*4096 + lane*16.
#define STAGEA(SB, Q, TI)                                                     \
  __builtin_amdgcn_global_load_lds(                                           \
      (const __attribute__((address_space(1))) void*)(const void*)(           \
          srcA + (TI) * BRICK + (Q) * 1024),                                  \
      (__attribute__((address_space(3))) void*)(void*)(                       \
          lds + (SB) + dA + (Q) * 1024),                                      \
      16, 0, 0)
#define STAGEB(SB, Q, TI)                                                     \
  __builtin_amdgcn_global_load_lds(                                           \
      (const __attribute__((address_space(1))) void*)(const void*)(           \
          srcB + (TI) * BRICK + (Q) * 1024),                                  \
      (__attribute__((address_space(3))) void*)(void*)(                       \
          lds + (SB) + dB + (Q) * 1024),                                      \
      16, 0, 0)

// Fragment read: two conflict-free ds_read_b128 (lane*16 stride) + combine.
#define LDA(OUT, RB, M)                                                       \
  {                                                                           \
    const unsigned char* _b = ldsL + ((RB) + ((wr * 4 + (M)) << 11));         \
    i32x4 _lo = *(const i32x4*)(_b);                                          \
    i32x4 _hi = *(const i32x4*)(_b + 1024);                                   \
    OUT = __builtin_shufflevector(_lo, _hi, 0, 1, 2, 3, 4, 5, 6, 7);          \
  }
#define LDB(OUT, RB, N)                                                       \
  {                                                                           \
    const unsigned char* _b = ldsL + ((RB) + 16384 + ((wc * 4 + (N)) << 11)); \
    i32x4 _lo = *(const i32x4*)(_b);                                          \
    i32x4 _hi = *(const i32x4*)(_b + 1024);                                   \
    OUT = __builtin_shufflevector(_lo, _hi, 0, 1, 2, 3, 4, 5, 6, 7);          \
  }

#define MFMA(AF, BF, M, N)                                                    \
  acc[M][N] = __builtin_amdgcn_mfma_scale_f32_16x16x128_f8f6f4(               \
      AF, BF, acc[M][N], 0, 0, 0, 127, 0, 127)

__global__ __launch_bounds__(256, 2) void siglip_gemm(
    const unsigned char* __restrict__ A8,
    const unsigned char* __restrict__ B8,
    float* __restrict__ partials) {
  __shared__ unsigned char lds[2 * BUFSZ];  // 64 KB double buffer
  __shared__ float wsum[4];

  const int tid = threadIdx.x;
  const int wave = tid >> 6;
  const int lane = tid & 63;
  const int wr = wave >> 1;  // 0..1 -> 64-row strip
  const int wc = wave & 1;   // 0..1 -> 64-col strip
  const int brow = blockIdx.y;
  const int bcol = blockIdx.x;

  f32x4 acc[4][4];
#pragma unroll
  for (int m = 0; m < 4; ++m)
#pragma unroll
    for (int n = 0; n < 4; ++n) acc[m][n] = f32x4{0.f, 0.f, 0.f, 0.f};

  const unsigned char* srcA =
      A8 + (size_t)brow * PANEL_BYTES + wave * 4096 + (lane << 4);
  const unsigned char* srcB =
      B8 + (size_t)bcol * PANEL_BYTES + wave * 4096 + (lane << 4);
  const int dA = wave * 4096;
  const int dB = 16384 + wave * 4096;
  const unsigned char* ldsL = lds + (lane << 4);  // per-lane read base

  // Prologue: stage tile 0 into buf 0, full drain, publish.
  STAGEA(0, 0, 0); STAGEA(0, 1, 0); STAGEA(0, 2, 0); STAGEA(0, 3, 0);
  STAGEB(0, 0, 0); STAGEB(0, 1, 0); STAGEB(0, 2, 0); STAGEB(0, 3, 0);
  asm volatile("s_waitcnt vmcnt(0)" ::: "memory");
  __builtin_amdgcn_s_barrier();
  __builtin_amdgcn_sched_barrier(0);

#pragma unroll
  for (int T = 0; T < NT; ++T) {
    const int rb = (T & 1) * BUFSZ;   // read buffer (tile T)
    const int sb = rb ^ BUFSZ;        // stage buffer (tile T+1; held T-1)

    // Stage tile T+1 first (VMEM, independent) so HBM/L2 latency hides
    // under everything below.
    if (T < NT - 1) {
      STAGEA(sb, 0, T + 1); STAGEA(sb, 1, T + 1);
      STAGEA(sb, 2, T + 1); STAGEA(sb, 3, T + 1);
      STAGEB(sb, 0, T + 1); STAGEB(sb, 1, T + 1);
      STAGEB(sb, 2, T + 1); STAGEB(sb, 3, T + 1);
    }

    // Fragment reads in consumption order; NO sched_barrier here: the
    // compiler interleaves MFMAs with counted lgkmcnt so the first MFMA
    // starts after ~2 reads instead of after all 16.
    i32x8 a0, a1, a2, a3, b0, b1, b2, b3;
    LDA(a0, rb, 0); LDB(b0, rb, 0); LDB(b1, rb, 1); LDB(b2, rb, 2);
    LDB(b3, rb, 3);
    LDA(a1, rb, 1); LDA(a2, rb, 2); LDA(a3, rb, 3);

    __builtin_amdgcn_s_setprio(1);
    MFMA(a0, b0, 0, 0); MFMA(a0, b1, 0, 1); MFMA(a0, b2, 0, 2); MFMA(a0, b3, 0, 3);
    MFMA(a1, b0, 1, 0); MFMA(a1, b1, 1, 1); MFMA(a1, b2, 1, 2); MFMA(a1, b3, 1, 3);
    MFMA(a2, b0, 2, 0); MFMA(a2, b1, 2, 1); MFMA(a2, b2, 2, 2); MFMA(a2, b3, 2, 3);
    MFMA(a3, b0, 3, 0); MFMA(a3, b1, 3, 1); MFMA(a3, b2, 3, 2); MFMA(a3, b3, 3, 3);
    __builtin_amdgcn_s_setprio(0);

    if (T < NT - 1) {
      // Own staging of T+1 landed (issued before reads+MFMAs -> covered);
      // barrier publishes all waves' staging and certifies tile T consumed.
      asm volatile("s_waitcnt vmcnt(0)" ::: "memory");
      __builtin_amdgcn_s_barrier();
      __builtin_amdgcn_sched_barrier(0);
    }
  }

  // Epilogue. C/D 16x16 map: col = lane&15, row = (lane>>4)*4 + r.
  const int rbase = brow * BT + wr * 64 + (lane >> 4) * 4;
  const int cbase = bcol * BT + wc * 64 + (lane & 15);
  float lsum;
  if (brow == bcol)
    lsum = softplus_sum<true>(acc, rbase, cbase);
  else
    lsum = softplus_sum<false>(acc, rbase, cbase);

#pragma unroll
  for (int off = 32; off > 0; off >>= 1) lsum += __shfl_down(lsum, off);
  __syncthreads();
  if (lane == 0) wsum[wave] = lsum;
  __syncthreads();
  if (tid == 0)
    partials[blockIdx.y * gridDim.x + blockIdx.x] =
        wsum[0] + wsum[1] + wsum[2] + wsum[3];
}

__global__ void reduce_kernel(const float* __restrict__ partials, int n,
                              float* __restrict__ out) {
  __shared__ float s[256];
  float v = 0.f;
  for (int i = threadIdx.x; i < n; i += 256) v += partials[i];
  s[threadIdx.x] = v;
  __syncthreads();
  for (int off = 128; off > 0; off >>= 1) {
    if ((int)threadIdx.x < off) s[threadIdx.x] += s[threadIdx.x + off];
    __syncthreads();
  }
  if (threadIdx.x == 0) out[0] = s[0] / (float)B_DIM;
}

extern "C" void kernel_launch(void* const* d_in, const int* in_sizes, int n_in,
                              void* d_out, int out_size, void* d_ws, size_t ws_size,
                              hipStream_t stream) {
  const float* emb1 = (const float*)d_in[0];
  const float* emb2 = (const float*)d_in[1];

  unsigned char* A8 = (unsigned char*)d_ws;                // 8 MB (bricked)
  unsigned char* B8 = A8 + (size_t)B_DIM * K_DIM;          // 8 MB (bricked)
  float* partials = (float*)(B8 + (size_t)B_DIM * K_DIM);  // 16 KB

  const float INV_T = 1.0f / 0.07f;
  const int nbA = (B_DIM * K_DIM / 16) / 256;  // 2048 blocks per operand
  cvt_fused<<<2 * nbA, 256, 0, stream>>>(emb1, emb2, A8, B8, nbA, INV_T);

  dim3 grid(B_DIM / BT, B_DIM / BT);  // 64 x 64
  siglip_gemm<<<grid, 256, 0, stream>>>(A8, B8, partials);

  const int nparts = (B_DIM / BT) * (B_DIM / BT);
  reduce_kernel<<<1, 256, 0, stream>>>(partials, nparts, (float*)d_out);
}